// Round 11
// baseline (406.640 us; speedup 1.0000x reference)
//
#include <hip/hip_runtime.h>
#include <hip/hip_bf16.h>

typedef __bf16 bf16x8 __attribute__((ext_vector_type(8)));
typedef __bf16 bf16x4 __attribute__((ext_vector_type(4)));
typedef float f32x4 __attribute__((ext_vector_type(4)));
typedef float f32x8 __attribute__((ext_vector_type(8)));

#define B_ 8
#define L_ 1024
#define D_ 1024
#define H_ 16
#define DPH_ 64
#define MAXREL_ 32
#define NREL_ 65

__device__ __forceinline__ f32x4 mfma16x16x32(bf16x8 a, bf16x8 b, f32x4 c) {
    return __builtin_amdgcn_mfma_f32_16x16x32_bf16(a, b, c, 0, 0, 0);
}

__device__ __forceinline__ bf16x8 ld_any(const float* p) {
    f32x8 v = *(const f32x8*)p;
    bf16x8 r;
    #pragma unroll
    for (int i = 0; i < 8; ++i) r[i] = (__bf16)v[i];
    return r;
}
__device__ __forceinline__ bf16x8 ld_any(const __bf16* p) { return *(const bf16x8*)p; }

// ---------------------------------------------------------------------------
// gemm_v2 (R9): 128x256 tile, BK=32, 512 thr / 8 waves, dbuf LDS [rows][40].
// MODE 0: bf16 out[m*N+n]; MODE 1: bf16 Vt[(m>>10)<<20 | n*1024 | m&1023];
// MODE 2: f32 out[m*N+n].
// ---------------------------------------------------------------------------
template <int MODE, typename TA>
__global__ __launch_bounds__(512, 2) void gemm_v2(
    const TA* __restrict__ X, const float* __restrict__ Wt,
    const float* __restrict__ bias, void* __restrict__ outp,
    int M, int N, int K, float scale)
{
    __shared__ __bf16 sA[2][128 * 40];
    __shared__ __bf16 sB[2][256 * 40];

    const int tid = threadIdx.x;
    const int nbn = N >> 8;
    const int wg = (int)blockIdx.x;
    const int row0 = (wg / nbn) * 128, col0 = (wg % nbn) * 256;
    const int lane = tid & 63, w = tid >> 6, lr = lane & 15, lk = lane >> 4;
    const int wm = w >> 2, wn = w & 3;

    const int arow = tid >> 2, ak = (tid & 3) * 8;
    const int brow = tid >> 1, bk = (tid & 1) * 16;
    const TA*    agp = X  + (size_t)(row0 + arow) * K + ak;
    const float* bgp = Wt + (size_t)(col0 + brow) * K + bk;

    f32x4 acc[4][4];
    #pragma unroll
    for (int a = 0; a < 4; ++a)
        #pragma unroll
        for (int b = 0; b < 4; ++b) acc[a][b] = (f32x4){0.f, 0.f, 0.f, 0.f};

    f32x4 ra0, ra1;
    bf16x8 rab;
    f32x4 rb0, rb1, rb2, rb3;

    #define LOADG(t) do {                                                    \
        const int _k0 = (t) * 32;                                            \
        if (sizeof(TA) == 4) {                                               \
            ra0 = *(const f32x4*)((const float*)agp + _k0);                  \
            ra1 = *(const f32x4*)((const float*)agp + _k0 + 4);              \
        } else {                                                             \
            rab = *(const bf16x8*)((const __bf16*)agp + _k0);                \
        }                                                                    \
        rb0 = *(const f32x4*)(bgp + _k0);                                    \
        rb1 = *(const f32x4*)(bgp + _k0 + 4);                                \
        rb2 = *(const f32x4*)(bgp + _k0 + 8);                                \
        rb3 = *(const f32x4*)(bgp + _k0 + 12);                               \
    } while (0)

    #define WRITEL(buf) do {                                                 \
        bf16x8 _av;                                                          \
        if (sizeof(TA) == 4) {                                               \
            _Pragma("unroll")                                                \
            for (int i = 0; i < 4; ++i) {                                    \
                _av[i] = (__bf16)ra0[i]; _av[4 + i] = (__bf16)ra1[i];        \
            }                                                                \
        } else { _av = rab; }                                                \
        *(bf16x8*)&sA[buf][arow * 40 + ak] = _av;                            \
        bf16x8 _bv0, _bv1;                                                   \
        _Pragma("unroll")                                                    \
        for (int i = 0; i < 4; ++i) {                                        \
            _bv0[i] = (__bf16)rb0[i]; _bv0[4 + i] = (__bf16)rb1[i];          \
            _bv1[i] = (__bf16)rb2[i]; _bv1[4 + i] = (__bf16)rb3[i];          \
        }                                                                    \
        *(bf16x8*)&sB[buf][brow * 40 + bk]     = _bv0;                       \
        *(bf16x8*)&sB[buf][brow * 40 + bk + 8] = _bv1;                       \
    } while (0)

    LOADG(0);
    WRITEL(0);
    LOADG(1);
    __syncthreads();

    const int nkt = K >> 5;   // 32
    for (int t = 0; t < nkt; ++t) {
        const int cur = t & 1;
        bf16x8 af[4], bfr[4];
        #pragma unroll
        for (int m = 0; m < 4; ++m)
            af[m] = *(const bf16x8*)&sA[cur][(wm * 64 + m * 16 + lr) * 40 + 8 * lk];
        #pragma unroll
        for (int n = 0; n < 4; ++n)
            bfr[n] = *(const bf16x8*)&sB[cur][(wn * 64 + n * 16 + lr) * 40 + 8 * lk];
        __builtin_amdgcn_s_setprio(1);
        #pragma unroll
        for (int m = 0; m < 4; ++m)
            #pragma unroll
            for (int n = 0; n < 4; ++n)
                acc[m][n] = mfma16x16x32(af[m], bfr[n], acc[m][n]);
        __builtin_amdgcn_s_setprio(0);
        if (t < nkt - 1) {
            WRITEL(cur ^ 1);
            if (t < nkt - 2) LOADG(t + 2);
            __syncthreads();
        }
    }
    #undef LOADG
    #undef WRITEL

    #pragma unroll
    for (int ni = 0; ni < 4; ++ni) {
        const int n = col0 + wn * 64 + ni * 16 + lr;
        const float bv = bias[n];
        #pragma unroll
        for (int mi = 0; mi < 4; ++mi) {
            const int m0 = row0 + wm * 64 + mi * 16 + lk * 4;
            if (MODE == 0) {
                #pragma unroll
                for (int i = 0; i < 4; ++i)
                    ((__bf16*)outp)[(size_t)(m0 + i) * N + n] =
                        (__bf16)((acc[mi][ni][i] + bv) * scale);
            } else if (MODE == 1) {
                bf16x4 v4;
                #pragma unroll
                for (int i = 0; i < 4; ++i) v4[i] = (__bf16)(acc[mi][ni][i] + bv);
                *(bf16x4*)((__bf16*)outp + ((size_t)(m0 >> 10) << 20)
                           + (size_t)n * L_ + (m0 & 1023)) = v4;
            } else {
                #pragma unroll
                for (int i = 0; i < 4; ++i)
                    ((float*)outp)[(size_t)(m0 + i) * N + n] = acc[mi][ni][i] + bv;
            }
        }
    }
}

// ---------------------------------------------------------------------------
// Attention v7 = v5 minus V-staging (V is L2-resident; PV B-frags are
// contiguous 16B global loads issued right after QK^T so latency hides under
// the softmax VALU pass). LDS 51.7 -> 35.3KB => 4 blocks/CU (16 waves, 50%).
// Everything else is v5's verified path verbatim.
// ---------------------------------------------------------------------------
__global__ __launch_bounds__(256, 4) void attn_v7(
    const __bf16* __restrict__ Q, const __bf16* __restrict__ K,
    const __bf16* __restrict__ Vt, const int* __restrict__ mask,
    const float* __restrict__ relg, __bf16* __restrict__ ctx,
    float* __restrict__ attn0)
{
    __shared__ __bf16 sK[2][64 * 64];     // [key][d], chunk-swizzled
    __shared__ __bf16 s_rq[64 * 72];      // rq[qlocal][j], bf16
    __shared__ __bf16 s_arel[64 * 72];    // arel[qlocal][bucket], bf16
    __shared__ float s_sums[64];
    __shared__ unsigned s_mbits[32];

    const int tid = threadIdx.x;
    const int wg = ((int)blockIdx.x & 7) * 256 + ((int)blockIdx.x >> 3);
    const int qt = wg & 15, h = (wg >> 4) & 15, b = wg >> 8;
    const int q0 = qt * 64;
    const int lane = tid & 63, w = tid >> 6, lr = lane & 15, lk = lane >> 4;
    const size_t bh = (size_t)b * (L_ * D_) + (size_t)h * DPH_;
    const int qw = q0 + w * 16;           // wave's q base (global)
    const int ql = w * 16;                // wave's q base (block-local)

    const int strow = tid >> 3;                  // 0..31
    const int scg   = (tid & 7) ^ (strow & 7);   // pre-swizzled global chunk
    const __bf16* Kgp = K + bh + (size_t)strow * D_ + scg * 8;

    const __bf16* qp = Q + bh + (size_t)(qw + lr) * D_ + 8 * lk;
    const bf16x8 qf0 = *(const bf16x8*)qp;
    const bf16x8 qf1 = *(const bf16x8*)(qp + 32);

    #pragma unroll
    for (int rr = 0; rr < 4; ++rr) {
        const int k = rr * 256 + w * 64 + lane;
        const unsigned long long bal = __ballot(mask[b * L_ + k] != 0);
        if (lane == 0) {
            s_mbits[rr * 8 + w * 2]     = (unsigned)bal;
            s_mbits[rr * 8 + w * 2 + 1] = (unsigned)(bal >> 32);
        }
    }
    for (int i = tid; i < 64 * 72; i += 256) s_arel[i] = (__bf16)0.f;

    #pragma unroll
    for (int jt = 0; jt < 5; ++jt) {
        const int jr = jt * 16 + lr;
        const int jc = jr > 64 ? 64 : jr;
        const float* rp = relg + jc * 64 + 8 * lk;
        f32x4 rq = {0.f, 0.f, 0.f, 0.f};
        rq = mfma16x16x32(ld_any(rp), qf0, rq);
        rq = mfma16x16x32(ld_any(rp + 32), qf1, rq);
        #pragma unroll
        for (int i = 0; i < 4; ++i) {
            const int jj = jt * 16 + lk * 4 + i;
            if (jj <= 64) s_rq[(ql + lr) * 72 + jj] = (__bf16)rq[i];
        }
    }

    bf16x8 rk0 = *(const bf16x8*)(Kgp);
    bf16x8 rk1 = *(const bf16x8*)(Kgp + 32 * (size_t)D_);
    __syncthreads();

    const float rq0  = (float)s_rq[(ql + lr) * 72 + 0];
    const float rq64 = (float)s_rq[(ql + lr) * 72 + 64];

    float sum = 0.f, c0 = 0.f, c64 = 0.f;
    f32x4 pvacc[4];
    #pragma unroll
    for (int dt = 0; dt < 4; ++dt) pvacc[dt] = (f32x4){0.f, 0.f, 0.f, 0.f};
    float* a0p = attn0 + ((size_t)b * L_ + qw + lr) * L_;
    const int sw = lr & 7;
    const int s0l = lr + 32 * (lk & 1);
    const int s1l = s0l + 16;
    const bool hisel = (lk >> 1) != 0;

    // V direct-from-global base: row = h*64 + dt*16 + lr, elems k0+s*32+8*lk
    const __bf16* vrow = Vt + ((size_t)b << 20)
                       + (size_t)(h * DPH_ + lr) * L_ + 8 * lk;

    for (int it = 0; it < 16; ++it) {
        const int cur = it & 1;
        const int k0 = it * 64;
        {
            __bf16* kd = &sK[cur][tid * 8];
            *(bf16x8*)kd = rk0;  *(bf16x8*)(kd + 2048) = rk1;
        }
        __syncthreads();
        if (it < 15) {
            const size_t ko = (size_t)(k0 + 64) * D_;
            rk0 = *(const bf16x8*)(Kgp + ko);
            rk1 = *(const bf16x8*)(Kgp + ko + 32 * (size_t)D_);
        }

        const __bf16* kb = sK[cur];

        // ---- QK^T ----
        float p[4][4];
        #pragma unroll
        for (int kt = 0; kt < 4; ++kt) {
            const int rb = (kt * 16 + lr) * 64;
            const bf16x8 a0 = *(const bf16x8*)&kb[rb + ((lk ^ sw) * 8)];
            const bf16x8 a1 = *(const bf16x8*)&kb[rb + (((lk + 4) ^ sw) * 8)];
            f32x4 acc = {0.f, 0.f, 0.f, 0.f};
            acc = mfma16x16x32(a0, qf0, acc);
            acc = mfma16x16x32(a1, qf1, acc);
            #pragma unroll
            for (int i = 0; i < 4; ++i) p[kt][i] = acc[i];
        }

        // ---- issue V loads now; latency hides under softmax VALU ----
        bf16x8 vf[2][4];
        #pragma unroll
        for (int s = 0; s < 2; ++s)
            #pragma unroll
            for (int dt = 0; dt < 4; ++dt)
                vf[s][dt] = *(const bf16x8*)(vrow + (size_t)dt * 16 * L_
                                             + k0 + s * 32);

        // ---- bias + mask + exp + sums + arel ----
        const unsigned mw0 = s_mbits[(k0 >> 5)];
        const unsigned mw1 = s_mbits[(k0 >> 5) + 1];
        const int side = (k0 <= qw - 95) ? -1 : ((k0 >= qw + 47) ? 1 : 0);
        if (side == 0) {
            #pragma unroll
            for (int kt = 0; kt < 4; ++kt) {
                const unsigned mword = kt < 2 ? mw0 : mw1;
                #pragma unroll
                for (int i = 0; i < 4; ++i) {
                    const int k = k0 + kt * 16 + lk * 4 + i;
                    const int dd = k - (qw + lr);
                    int j = dd + MAXREL_;
                    j = j < 0 ? 0 : (j > 64 ? 64 : j);
                    const float bias = (float)s_rq[(ql + lr) * 72 + j];
                    const float e = ((mword >> (k & 31)) & 1u)
                                  ? 0.f : __expf(p[kt][i] + bias);
                    p[kt][i] = e;
                    sum += e;
                    if (dd <= -MAXREL_)      c0  += e;
                    else if (dd >= MAXREL_)  c64 += e;
                    else s_arel[(ql + lr) * 72 + dd + MAXREL_] = (__bf16)e;
                }
            }
        } else {
            const float bias = side < 0 ? rq0 : rq64;
            float cacc = 0.f;
            #pragma unroll
            for (int kt = 0; kt < 4; ++kt) {
                const unsigned mword = kt < 2 ? mw0 : mw1;
                #pragma unroll
                for (int i = 0; i < 4; ++i) {
                    const int k = k0 + kt * 16 + lk * 4 + i;
                    const float e = ((mword >> (k & 31)) & 1u)
                                  ? 0.f : __expf(p[kt][i] + bias);
                    p[kt][i] = e;
                    cacc += e;
                }
            }
            sum += cacc;
            if (side < 0) c0 += cacc; else c64 += cacc;
        }

        if (h == 0) {
            #pragma unroll
            for (int kt = 0; kt < 4; ++kt) {
                f32x4 st;
                #pragma unroll
                for (int i = 0; i < 4; ++i) st[i] = p[kt][i];
                *(f32x4*)&a0p[k0 + kt * 16 + lk * 4] = st;
            }
        }

        unsigned pk[4][2];
        #pragma unroll
        for (int kt = 0; kt < 4; ++kt)
            #pragma unroll
            for (int hf = 0; hf < 2; ++hf) {
                union { unsigned u; __bf16 x[2]; } t;
                t.x[0] = (__bf16)p[kt][2 * hf];
                t.x[1] = (__bf16)p[kt][2 * hf + 1];
                pk[kt][hf] = t.u;
            }

        // ---- PV: 2 x 32-key steps; A-frag via shuffles; B from registers ----
        #pragma unroll
        for (int s = 0; s < 2; ++s) {
            union { unsigned u[4]; bf16x8 v; } ua;
            {
                const unsigned aE0 = __shfl((int)pk[2 * s][0],     s0l, 64);
                const unsigned aO0 = __shfl((int)pk[2 * s + 1][0], s0l, 64);
                const unsigned aE1 = __shfl((int)pk[2 * s][1],     s0l, 64);
                const unsigned aO1 = __shfl((int)pk[2 * s + 1][1], s0l, 64);
                const unsigned bE0 = __shfl((int)pk[2 * s][0],     s1l, 64);
                const unsigned bO0 = __shfl((int)pk[2 * s + 1][0], s1l, 64);
                const unsigned bE1 = __shfl((int)pk[2 * s][1],     s1l, 64);
                const unsigned bO1 = __shfl((int)pk[2 * s + 1][1], s1l, 64);
                ua.u[0] = hisel ? aO0 : aE0;
                ua.u[1] = hisel ? aO1 : aE1;
                ua.u[2] = hisel ? bO0 : bE0;
                ua.u[3] = hisel ? bO1 : bE1;
            }
            #pragma unroll
            for (int dt = 0; dt < 4; ++dt)
                pvacc[dt] = mfma16x16x32(ua.v, vf[s][dt], pvacc[dt]);
        }
    }

    sum += __shfl_xor(sum, 16, 64); sum += __shfl_xor(sum, 32, 64);
    c0  += __shfl_xor(c0, 16, 64);  c0  += __shfl_xor(c0, 32, 64);
    c64 += __shfl_xor(c64, 16, 64); c64 += __shfl_xor(c64, 32, 64);
    if (lane < 16) {
        s_sums[ql + lr] = sum;
        s_arel[(ql + lr) * 72 + 0]  = (__bf16)c0;
        s_arel[(ql + lr) * 72 + 64] = (__bf16)c64;
    }
    __syncthreads();

    __bf16* rT = (__bf16*)sK;      // [64][72]
    for (int i = tid; i < NREL_ * DPH_; i += 256)
        rT[(i & 63) * 72 + (i >> 6)] = (__bf16)relg[i];
    __syncthreads();

    const bf16x8 af1 = *(const bf16x8*)&s_arel[(ql + lr) * 72 + 8 * lk];
    const bf16x8 af2 = *(const bf16x8*)&s_arel[(ql + lr) * 72 + 32 + 8 * lk];
    float a64[4], inv[4];
    #pragma unroll
    for (int i = 0; i < 4; ++i) {
        a64[i] = (float)s_arel[(ql + lk * 4 + i) * 72 + 64];
        inv[i] = 1.f / s_sums[ql + lk * 4 + i];
    }
    #pragma unroll
    for (int dt = 0; dt < 4; ++dt) {
        const bf16x8 b1 = *(const bf16x8*)&rT[(dt * 16 + lr) * 72 + 8 * lk];
        const bf16x8 b2 = *(const bf16x8*)&rT[(dt * 16 + lr) * 72 + 32 + 8 * lk];
        pvacc[dt] = mfma16x16x32(af1, b1, pvacc[dt]);
        pvacc[dt] = mfma16x16x32(af2, b2, pvacc[dt]);
        const float r64 = (float)rT[(dt * 16 + lr) * 72 + 64];
        #pragma unroll
        for (int i = 0; i < 4; ++i) {
            const float outv = (pvacc[dt][i] + a64[i] * r64) * inv[i];
            ctx[((size_t)b * L_ + q0 + ql + lk * 4 + i) * D_
                + h * DPH_ + dt * 16 + lr] = (__bf16)outv;
        }
    }

    if (h == 0) {
        #pragma unroll 4
        for (int n = 0; n < 16; ++n) {
            const float invr = 1.f / s_sums[ql + n];
            float* ap = attn0 + ((size_t)b * L_ + q0 + ql + n) * L_ + lane * 16;
            #pragma unroll
            for (int c = 0; c < 4; ++c) {
                f32x4 v = *(f32x4*)&ap[c * 4];
                #pragma unroll
                for (int i = 0; i < 4; ++i) v[i] *= invr;
                *(f32x4*)&ap[c * 4] = v;
            }
        }
    }
}

extern "C" void kernel_launch(void* const* d_in, const int* in_sizes, int n_in,
                              void* d_out, int out_size, void* d_ws, size_t ws_size,
                              hipStream_t stream) {
    const float* key   = (const float*)d_in[0];
    const float* value = (const float*)d_in[1];
    const float* query = (const float*)d_in[2];
    const int*   mask  = (const int*)d_in[3];
    const float* Wq = (const float*)d_in[4];
    const float* bq = (const float*)d_in[5];
    const float* Wk = (const float*)d_in[6];
    const float* bk = (const float*)d_in[7];
    const float* Wv = (const float*)d_in[8];
    const float* bv = (const float*)d_in[9];
    const float* Wo = (const float*)d_in[10];
    const float* bo = (const float*)d_in[11];
    const float* relg = (const float*)d_in[12];

    float* out   = (float*)d_out;
    float* attn0 = out + (size_t)B_ * L_ * D_;

    char* ws = (char*)d_ws;
    __bf16* Qw   = (__bf16*)(ws);
    __bf16* Kw   = (__bf16*)(ws + ((size_t)16 << 20));
    __bf16* Vtw  = (__bf16*)(ws + ((size_t)32 << 20));
    __bf16* Ctxw = (__bf16*)(ws + ((size_t)48 << 20));

    const int M = B_ * L_;
    const int ngemm = (M / 128) * (D_ / 256);   // 256 blocks = 1/CU

    gemm_v2<0, float><<<ngemm, dim3(512), 0, stream>>>(query, Wq, bq, Qw, M, D_, D_, 0.125f);
    gemm_v2<0, float><<<ngemm, dim3(512), 0, stream>>>(key,   Wk, bk, Kw, M, D_, D_, 1.0f);
    gemm_v2<1, float><<<ngemm, dim3(512), 0, stream>>>(value, Wv, bv, Vtw, M, D_, D_, 1.0f);

    attn_v7<<<B_ * H_ * (L_ / 64), dim3(256), 0, stream>>>(
        Qw, Kw, Vtw, mask, relg, Ctxw, attn0);

    gemm_v2<2, __bf16><<<ngemm, dim3(512), 0, stream>>>(Ctxw, Wo, bo, out, M, D_, D_, 1.0f);
}

// Round 12
// 262.132 us; speedup vs baseline: 1.5513x; 1.5513x over previous
//
#include <hip/hip_runtime.h>
#include <hip/hip_bf16.h>

typedef __bf16 bf16x8 __attribute__((ext_vector_type(8)));
typedef __bf16 bf16x4 __attribute__((ext_vector_type(4)));
typedef float f32x4 __attribute__((ext_vector_type(4)));
typedef float f32x8 __attribute__((ext_vector_type(8)));

#define B_ 8
#define L_ 1024
#define D_ 1024
#define H_ 16
#define DPH_ 64
#define MAXREL_ 32
#define NREL_ 65

__device__ __forceinline__ f32x4 mfma16x16x32(bf16x8 a, bf16x8 b, f32x4 c) {
    return __builtin_amdgcn_mfma_f32_16x16x32_bf16(a, b, c, 0, 0, 0);
}

__device__ __forceinline__ bf16x8 ld_any(const float* p) {
    f32x8 v = *(const f32x8*)p;
    bf16x8 r;
    #pragma unroll
    for (int i = 0; i < 8; ++i) r[i] = (__bf16)v[i];
    return r;
}
__device__ __forceinline__ bf16x8 ld_any(const __bf16* p) { return *(const bf16x8*)p; }

// ---------------------------------------------------------------------------
// gemm_v2 (R9, measured 27.5us each): 128x256 tile, BK=32, 512 thr / 8 waves,
// dbuf LDS [rows][40]. MODE 0: bf16 out; MODE 1: bf16 Vt transpose; MODE 2: f32.
// ---------------------------------------------------------------------------
template <int MODE, typename TA>
__global__ __launch_bounds__(512, 2) void gemm_v2(
    const TA* __restrict__ X, const float* __restrict__ Wt,
    const float* __restrict__ bias, void* __restrict__ outp,
    int M, int N, int K, float scale)
{
    __shared__ __bf16 sA[2][128 * 40];
    __shared__ __bf16 sB[2][256 * 40];

    const int tid = threadIdx.x;
    const int nbn = N >> 8;
    const int wg = (int)blockIdx.x;
    const int row0 = (wg / nbn) * 128, col0 = (wg % nbn) * 256;
    const int lane = tid & 63, w = tid >> 6, lr = lane & 15, lk = lane >> 4;
    const int wm = w >> 2, wn = w & 3;

    const int arow = tid >> 2, ak = (tid & 3) * 8;
    const int brow = tid >> 1, bk = (tid & 1) * 16;
    const TA*    agp = X  + (size_t)(row0 + arow) * K + ak;
    const float* bgp = Wt + (size_t)(col0 + brow) * K + bk;

    f32x4 acc[4][4];
    #pragma unroll
    for (int a = 0; a < 4; ++a)
        #pragma unroll
        for (int b = 0; b < 4; ++b) acc[a][b] = (f32x4){0.f, 0.f, 0.f, 0.f};

    f32x4 ra0, ra1;
    bf16x8 rab;
    f32x4 rb0, rb1, rb2, rb3;

    #define LOADG(t) do {                                                    \
        const int _k0 = (t) * 32;                                            \
        if (sizeof(TA) == 4) {                                               \
            ra0 = *(const f32x4*)((const float*)agp + _k0);                  \
            ra1 = *(const f32x4*)((const float*)agp + _k0 + 4);              \
        } else {                                                             \
            rab = *(const bf16x8*)((const __bf16*)agp + _k0);                \
        }                                                                    \
        rb0 = *(const f32x4*)(bgp + _k0);                                    \
        rb1 = *(const f32x4*)(bgp + _k0 + 4);                                \
        rb2 = *(const f32x4*)(bgp + _k0 + 8);                                \
        rb3 = *(const f32x4*)(bgp + _k0 + 12);                               \
    } while (0)

    #define WRITEL(buf) do {                                                 \
        bf16x8 _av;                                                          \
        if (sizeof(TA) == 4) {                                               \
            _Pragma("unroll")                                                \
            for (int i = 0; i < 4; ++i) {                                    \
                _av[i] = (__bf16)ra0[i]; _av[4 + i] = (__bf16)ra1[i];        \
            }                                                                \
        } else { _av = rab; }                                                \
        *(bf16x8*)&sA[buf][arow * 40 + ak] = _av;                            \
        bf16x8 _bv0, _bv1;                                                   \
        _Pragma("unroll")                                                    \
        for (int i = 0; i < 4; ++i) {                                        \
            _bv0[i] = (__bf16)rb0[i]; _bv0[4 + i] = (__bf16)rb1[i];          \
            _bv1[i] = (__bf16)rb2[i]; _bv1[4 + i] = (__bf16)rb3[i];          \
        }                                                                    \
        *(bf16x8*)&sB[buf][brow * 40 + bk]     = _bv0;                       \
        *(bf16x8*)&sB[buf][brow * 40 + bk + 8] = _bv1;                       \
    } while (0)

    LOADG(0);
    WRITEL(0);
    LOADG(1);
    __syncthreads();

    const int nkt = K >> 5;   // 32
    for (int t = 0; t < nkt; ++t) {
        const int cur = t & 1;
        bf16x8 af[4], bfr[4];
        #pragma unroll
        for (int m = 0; m < 4; ++m)
            af[m] = *(const bf16x8*)&sA[cur][(wm * 64 + m * 16 + lr) * 40 + 8 * lk];
        #pragma unroll
        for (int n = 0; n < 4; ++n)
            bfr[n] = *(const bf16x8*)&sB[cur][(wn * 64 + n * 16 + lr) * 40 + 8 * lk];
        __builtin_amdgcn_s_setprio(1);
        #pragma unroll
        for (int m = 0; m < 4; ++m)
            #pragma unroll
            for (int n = 0; n < 4; ++n)
                acc[m][n] = mfma16x16x32(af[m], bfr[n], acc[m][n]);
        __builtin_amdgcn_s_setprio(0);
        if (t < nkt - 1) {
            WRITEL(cur ^ 1);
            if (t < nkt - 2) LOADG(t + 2);
            __syncthreads();
        }
    }
    #undef LOADG
    #undef WRITEL

    #pragma unroll
    for (int ni = 0; ni < 4; ++ni) {
        const int n = col0 + wn * 64 + ni * 16 + lr;
        const float bv = bias[n];
        #pragma unroll
        for (int mi = 0; mi < 4; ++mi) {
            const int m0 = row0 + wm * 64 + mi * 16 + lk * 4;
            if (MODE == 0) {
                #pragma unroll
                for (int i = 0; i < 4; ++i)
                    ((__bf16*)outp)[(size_t)(m0 + i) * N + n] =
                        (__bf16)((acc[mi][ni][i] + bv) * scale);
            } else if (MODE == 1) {
                bf16x4 v4;
                #pragma unroll
                for (int i = 0; i < 4; ++i) v4[i] = (__bf16)(acc[mi][ni][i] + bv);
                *(bf16x4*)((__bf16*)outp + ((size_t)(m0 >> 10) << 20)
                           + (size_t)n * L_ + (m0 & 1023)) = v4;
            } else {
                #pragma unroll
                for (int i = 0; i < 4; ++i)
                    ((float*)outp)[(size_t)(m0 + i) * N + n] = acc[mi][ni][i] + bv;
            }
        }
    }
}

// ---------------------------------------------------------------------------
// Attention v8 = v5 structure with 32 q-rows per wave (two q-halves sharing
// every staged K/V read): LDS traffic and staging/barriers per unit work
// halve. Block = (b, h, 128 q-rows), 4 waves, grid 1024. All primitives are
// v5-verified, applied per half. LDS ~70KB -> 2 blocks/CU.
// ---------------------------------------------------------------------------
__global__ __launch_bounds__(256, 2) void attn_v8(
    const __bf16* __restrict__ Q, const __bf16* __restrict__ K,
    const __bf16* __restrict__ Vt, const int* __restrict__ mask,
    const float* __restrict__ relg, __bf16* __restrict__ ctx,
    float* __restrict__ attn0)
{
    __shared__ __bf16 sK[2][64 * 64];     // [key][d], chunk-swizzled
    __shared__ __bf16 sV[2][64 * 64];     // [d][key], chunk-swizzled
    __shared__ __bf16 s_rq[128 * 72];     // rq[qlocal][j], bf16
    __shared__ __bf16 s_arel[128 * 72];   // arel[qlocal][bucket], bf16
    __shared__ float s_sums[128];
    __shared__ unsigned s_mbits[32];

    const int tid = threadIdx.x;
    const int wg = ((int)blockIdx.x & 7) * 128 + ((int)blockIdx.x >> 3);
    const int qt = wg & 7, h = (wg >> 3) & 15, b = wg >> 7;
    const int q0 = qt * 128;
    const int lane = tid & 63, w = tid >> 6, lr = lane & 15, lk = lane >> 4;
    const size_t bh = (size_t)b * (L_ * D_) + (size_t)h * DPH_;
    const int ql = w * 32;                // wave's q base (block-local)
    const int qw = q0 + ql;               // wave's q base (global)

    const int strow = tid >> 3;                  // 0..31
    const int scg   = (tid & 7) ^ (strow & 7);   // pre-swizzled global chunk
    const __bf16* Kgp = K + bh + (size_t)strow * D_ + scg * 8;
    const __bf16* Vgp = Vt + ((size_t)b << 20)
                      + (size_t)(h * DPH_ + strow) * L_ + scg * 8;

    // Q fragments for both q-halves: lane lr -> q-row qw + half*16 + lr
    bf16x8 qf[2][2];
    #pragma unroll
    for (int hf = 0; hf < 2; ++hf) {
        const __bf16* qp = Q + bh + (size_t)(qw + hf * 16 + lr) * D_ + 8 * lk;
        qf[hf][0] = *(const bf16x8*)qp;
        qf[hf][1] = *(const bf16x8*)(qp + 32);
    }

    #pragma unroll
    for (int rr = 0; rr < 4; ++rr) {
        const int k = rr * 256 + w * 64 + lane;
        const unsigned long long bal = __ballot(mask[b * L_ + k] != 0);
        if (lane == 0) {
            s_mbits[rr * 8 + w * 2]     = (unsigned)bal;
            s_mbits[rr * 8 + w * 2 + 1] = (unsigned)(bal >> 32);
        }
    }
    for (int i = tid; i < 128 * 72; i += 256) s_arel[i] = (__bf16)0.f;

    // rq[q][j] = q . rel_emb[j] via MFMA, per half
    #pragma unroll
    for (int hf = 0; hf < 2; ++hf)
        #pragma unroll
        for (int jt = 0; jt < 5; ++jt) {
            const int jr = jt * 16 + lr;
            const int jc = jr > 64 ? 64 : jr;
            const float* rp = relg + jc * 64 + 8 * lk;
            f32x4 rq = {0.f, 0.f, 0.f, 0.f};
            rq = mfma16x16x32(ld_any(rp), qf[hf][0], rq);
            rq = mfma16x16x32(ld_any(rp + 32), qf[hf][1], rq);
            #pragma unroll
            for (int i = 0; i < 4; ++i) {
                const int jj = jt * 16 + lk * 4 + i;
                if (jj <= 64) s_rq[(ql + hf * 16 + lr) * 72 + jj] = (__bf16)rq[i];
            }
        }

    bf16x8 rk0 = *(const bf16x8*)(Kgp);
    bf16x8 rk1 = *(const bf16x8*)(Kgp + 32 * (size_t)D_);
    bf16x8 rv0 = *(const bf16x8*)(Vgp);
    bf16x8 rv1 = *(const bf16x8*)(Vgp + 32 * (size_t)L_);
    __syncthreads();

    float rq0[2], rq64[2];
    #pragma unroll
    for (int hf = 0; hf < 2; ++hf) {
        rq0[hf]  = (float)s_rq[(ql + hf * 16 + lr) * 72 + 0];
        rq64[hf] = (float)s_rq[(ql + hf * 16 + lr) * 72 + 64];
    }

    float sum0 = 0.f, sum1 = 0.f, c0a = 0.f, c0b = 0.f, c64a = 0.f, c64b = 0.f;
    f32x4 pvA[4], pvB[4];
    #pragma unroll
    for (int dt = 0; dt < 4; ++dt) {
        pvA[dt] = (f32x4){0.f, 0.f, 0.f, 0.f};
        pvB[dt] = (f32x4){0.f, 0.f, 0.f, 0.f};
    }
    const int sw = lr & 7;
    const int s0l = lr + 32 * (lk & 1);
    const int s1l = s0l + 16;
    const bool hisel = (lk >> 1) != 0;

    for (int it = 0; it < 16; ++it) {
        const int cur = it & 1;
        const int k0 = it * 64;
        {
            __bf16* kd = &sK[cur][tid * 8];
            __bf16* vd = &sV[cur][tid * 8];
            *(bf16x8*)kd = rk0;  *(bf16x8*)(kd + 2048) = rk1;
            *(bf16x8*)vd = rv0;  *(bf16x8*)(vd + 2048) = rv1;
        }
        __syncthreads();
        if (it < 15) {
            const size_t ko = (size_t)(k0 + 64) * D_;
            rk0 = *(const bf16x8*)(Kgp + ko);
            rk1 = *(const bf16x8*)(Kgp + ko + 32 * (size_t)D_);
            rv0 = *(const bf16x8*)(Vgp + k0 + 64);
            rv1 = *(const bf16x8*)(Vgp + k0 + 64 + 32 * (size_t)L_);
        }

        const __bf16* kb = sK[cur];
        const __bf16* vb = sV[cur];

        // ---- QK^T: shared K-reads feed both q-halves ----
        float p[2][4][4];
        #pragma unroll
        for (int kt = 0; kt < 4; ++kt) {
            const int rb = (kt * 16 + lr) * 64;
            const bf16x8 a0 = *(const bf16x8*)&kb[rb + ((lk ^ sw) * 8)];
            const bf16x8 a1 = *(const bf16x8*)&kb[rb + (((lk + 4) ^ sw) * 8)];
            #pragma unroll
            for (int hf = 0; hf < 2; ++hf) {
                f32x4 acc = {0.f, 0.f, 0.f, 0.f};
                acc = mfma16x16x32(a0, qf[hf][0], acc);
                acc = mfma16x16x32(a1, qf[hf][1], acc);
                #pragma unroll
                for (int i = 0; i < 4; ++i) p[hf][kt][i] = acc[i];
            }
        }

        // ---- bias + mask + exp + sums + arel (per half) ----
        const unsigned mw0 = s_mbits[(k0 >> 5)];
        const unsigned mw1 = s_mbits[(k0 >> 5) + 1];
        const int side = (k0 <= qw - 95) ? -1 : ((k0 >= qw + 63) ? 1 : 0);
        #pragma unroll
        for (int hf = 0; hf < 2; ++hf) {
            const int qg = qw + hf * 16 + lr;         // this lane's q (global)
            const int rqrow = (ql + hf * 16 + lr) * 72;
            if (side == 0) {
                float lsum = 0.f, lc0 = 0.f, lc64 = 0.f;
                #pragma unroll
                for (int kt = 0; kt < 4; ++kt) {
                    const unsigned mword = kt < 2 ? mw0 : mw1;
                    #pragma unroll
                    for (int i = 0; i < 4; ++i) {
                        const int k = k0 + kt * 16 + lk * 4 + i;
                        const int dd = k - qg;
                        int j = dd + MAXREL_;
                        j = j < 0 ? 0 : (j > 64 ? 64 : j);
                        const float bias = (float)s_rq[rqrow + j];
                        const float e = ((mword >> (k & 31)) & 1u)
                                      ? 0.f : __expf(p[hf][kt][i] + bias);
                        p[hf][kt][i] = e;
                        lsum += e;
                        if (dd <= -MAXREL_)      lc0  += e;
                        else if (dd >= MAXREL_)  lc64 += e;
                        else s_arel[rqrow + dd + MAXREL_] = (__bf16)e;
                    }
                }
                if (hf == 0) { sum0 += lsum; c0a += lc0; c64a += lc64; }
                else         { sum1 += lsum; c0b += lc0; c64b += lc64; }
            } else {
                const float bias = side < 0 ? rq0[hf] : rq64[hf];
                float cacc = 0.f;
                #pragma unroll
                for (int kt = 0; kt < 4; ++kt) {
                    const unsigned mword = kt < 2 ? mw0 : mw1;
                    #pragma unroll
                    for (int i = 0; i < 4; ++i) {
                        const int k = k0 + kt * 16 + lk * 4 + i;
                        const float e = ((mword >> (k & 31)) & 1u)
                                      ? 0.f : __expf(p[hf][kt][i] + bias);
                        p[hf][kt][i] = e;
                        cacc += e;
                    }
                }
                if (hf == 0) {
                    sum0 += cacc;
                    if (side < 0) c0a += cacc; else c64a += cacc;
                } else {
                    sum1 += cacc;
                    if (side < 0) c0b += cacc; else c64b += cacc;
                }
            }
        }

        // ---- attn0 (h==0): unnormalized now, rescaled at end ----
        if (h == 0) {
            #pragma unroll
            for (int hf = 0; hf < 2; ++hf) {
                float* a0p = attn0 + ((size_t)b * L_ + qw + hf * 16 + lr) * L_;
                #pragma unroll
                for (int kt = 0; kt < 4; ++kt) {
                    f32x4 st;
                    #pragma unroll
                    for (int i = 0; i < 4; ++i) st[i] = p[hf][kt][i];
                    *(f32x4*)&a0p[k0 + kt * 16 + lk * 4] = st;
                }
            }
        }

        // ---- pack p -> bf16 pairs (per half) ----
        unsigned pk[2][4][2];
        #pragma unroll
        for (int hf = 0; hf < 2; ++hf)
            #pragma unroll
            for (int kt = 0; kt < 4; ++kt)
                #pragma unroll
                for (int pf = 0; pf < 2; ++pf) {
                    union { unsigned u; __bf16 x[2]; } t;
                    t.x[0] = (__bf16)p[hf][kt][2 * pf];
                    t.x[1] = (__bf16)p[hf][kt][2 * pf + 1];
                    pk[hf][kt][pf] = t.u;
                }

        // ---- PV: shared V-reads feed both halves' MFMAs ----
        #pragma unroll
        for (int s = 0; s < 2; ++s) {
            union { unsigned u[4]; bf16x8 v; } uaA, uaB;
            #pragma unroll
            for (int hf = 0; hf < 2; ++hf) {
                const unsigned aE0 = __shfl((int)pk[hf][2 * s][0],     s0l, 64);
                const unsigned aO0 = __shfl((int)pk[hf][2 * s + 1][0], s0l, 64);
                const unsigned aE1 = __shfl((int)pk[hf][2 * s][1],     s0l, 64);
                const unsigned aO1 = __shfl((int)pk[hf][2 * s + 1][1], s0l, 64);
                const unsigned bE0 = __shfl((int)pk[hf][2 * s][0],     s1l, 64);
                const unsigned bO0 = __shfl((int)pk[hf][2 * s + 1][0], s1l, 64);
                const unsigned bE1 = __shfl((int)pk[hf][2 * s][1],     s1l, 64);
                const unsigned bO1 = __shfl((int)pk[hf][2 * s + 1][1], s1l, 64);
                unsigned u0 = hisel ? aO0 : aE0;
                unsigned u1 = hisel ? aO1 : aE1;
                unsigned u2 = hisel ? bO0 : bE0;
                unsigned u3 = hisel ? bO1 : bE1;
                if (hf == 0) { uaA.u[0]=u0; uaA.u[1]=u1; uaA.u[2]=u2; uaA.u[3]=u3; }
                else         { uaB.u[0]=u0; uaB.u[1]=u1; uaB.u[2]=u2; uaB.u[3]=u3; }
            }
            #pragma unroll
            for (int dt = 0; dt < 4; ++dt) {
                const bf16x8 bfv = *(const bf16x8*)
                    &vb[(dt * 16 + lr) * 64 + (((4 * s + lk) ^ sw) * 8)];
                pvA[dt] = mfma16x16x32(uaA.v, bfv, pvA[dt]);
                pvB[dt] = mfma16x16x32(uaB.v, bfv, pvB[dt]);
            }
        }
    }

    // ---- wave-local sums + edge buckets (per half) ----
    sum0 += __shfl_xor(sum0, 16, 64); sum0 += __shfl_xor(sum0, 32, 64);
    sum1 += __shfl_xor(sum1, 16, 64); sum1 += __shfl_xor(sum1, 32, 64);
    c0a  += __shfl_xor(c0a, 16, 64);  c0a  += __shfl_xor(c0a, 32, 64);
    c0b  += __shfl_xor(c0b, 16, 64);  c0b  += __shfl_xor(c0b, 32, 64);
    c64a += __shfl_xor(c64a, 16, 64); c64a += __shfl_xor(c64a, 32, 64);
    c64b += __shfl_xor(c64b, 16, 64); c64b += __shfl_xor(c64b, 32, 64);
    if (lane < 16) {
        s_sums[ql + lr] = sum0;
        s_sums[ql + 16 + lr] = sum1;
        s_arel[(ql + lr) * 72 + 0]       = (__bf16)c0a;
        s_arel[(ql + lr) * 72 + 64]      = (__bf16)c64a;
        s_arel[(ql + 16 + lr) * 72 + 0]  = (__bf16)c0b;
        s_arel[(ql + 16 + lr) * 72 + 64] = (__bf16)c64b;
    }
    __syncthreads();

    // ---- stage relT[d][j] over sK arena ----
    __bf16* rT = (__bf16*)sK;      // [64][72]
    for (int i = tid; i < NREL_ * DPH_; i += 256)
        rT[(i & 63) * 72 + (i >> 6)] = (__bf16)relg[i];
    __syncthreads();

    // ---- rel-term MFMAs + j=64 rank-1 + normalize + store ctx (per half) ----
    #pragma unroll
    for (int hf = 0; hf < 2; ++hf) {
        const int qrow = ql + hf * 16;
        const bf16x8 af1 = *(const bf16x8*)&s_arel[(qrow + lr) * 72 + 8 * lk];
        const bf16x8 af2 = *(const bf16x8*)&s_arel[(qrow + lr) * 72 + 32 + 8 * lk];
        float a64[4], inv[4];
        #pragma unroll
        for (int i = 0; i < 4; ++i) {
            a64[i] = (float)s_arel[(qrow + lk * 4 + i) * 72 + 64];
            inv[i] = 1.f / s_sums[qrow + lk * 4 + i];
        }
        #pragma unroll
        for (int dt = 0; dt < 4; ++dt) {
            f32x4 pv = hf == 0 ? pvA[dt] : pvB[dt];
            const bf16x8 b1 = *(const bf16x8*)&rT[(dt * 16 + lr) * 72 + 8 * lk];
            const bf16x8 b2 = *(const bf16x8*)&rT[(dt * 16 + lr) * 72 + 32 + 8 * lk];
            pv = mfma16x16x32(af1, b1, pv);
            pv = mfma16x16x32(af2, b2, pv);
            const float r64 = (float)rT[(dt * 16 + lr) * 72 + 64];
            #pragma unroll
            for (int i = 0; i < 4; ++i) {
                const float outv = (pv[i] + a64[i] * r64) * inv[i];
                ctx[((size_t)b * L_ + q0 + qrow + lk * 4 + i) * D_
                    + h * DPH_ + dt * 16 + lr] = (__bf16)outv;
            }
        }
    }

    // ---- attn0 rescale (h==0 blocks only), 32 rows per wave ----
    if (h == 0) {
        #pragma unroll 4
        for (int n = 0; n < 32; ++n) {
            const float invr = 1.f / s_sums[ql + n];
            float* ap = attn0 + ((size_t)b * L_ + q0 + ql + n) * L_ + lane * 16;
            #pragma unroll
            for (int c = 0; c < 4; ++c) {
                f32x4 v = *(f32x4*)&ap[c * 4];
                #pragma unroll
                for (int i = 0; i < 4; ++i) v[i] *= invr;
                *(f32x4*)&ap[c * 4] = v;
            }
        }
    }
}

extern "C" void kernel_launch(void* const* d_in, const int* in_sizes, int n_in,
                              void* d_out, int out_size, void* d_ws, size_t ws_size,
                              hipStream_t stream) {
    const float* key   = (const float*)d_in[0];
    const float* value = (const float*)d_in[1];
    const float* query = (const float*)d_in[2];
    const int*   mask  = (const int*)d_in[3];
    const float* Wq = (const float*)d_in[4];
    const float* bq = (const float*)d_in[5];
    const float* Wk = (const float*)d_in[6];
    const float* bk = (const float*)d_in[7];
    const float* Wv = (const float*)d_in[8];
    const float* bv = (const float*)d_in[9];
    const float* Wo = (const float*)d_in[10];
    const float* bo = (const float*)d_in[11];
    const float* relg = (const float*)d_in[12];

    float* out   = (float*)d_out;
    float* attn0 = out + (size_t)B_ * L_ * D_;

    char* ws = (char*)d_ws;
    __bf16* Qw   = (__bf16*)(ws);
    __bf16* Kw   = (__bf16*)(ws + ((size_t)16 << 20));
    __bf16* Vtw  = (__bf16*)(ws + ((size_t)32 << 20));
    __bf16* Ctxw = (__bf16*)(ws + ((size_t)48 << 20));

    const int M = B_ * L_;
    const int ngemm = (M / 128) * (D_ / 256);   // 256 blocks = 1/CU

    gemm_v2<0, float><<<ngemm, dim3(512), 0, stream>>>(query, Wq, bq, Qw, M, D_, D_, 0.125f);
    gemm_v2<0, float><<<ngemm, dim3(512), 0, stream>>>(key,   Wk, bk, Kw, M, D_, D_, 1.0f);
    gemm_v2<1, float><<<ngemm, dim3(512), 0, stream>>>(value, Wv, bv, Vtw, M, D_, D_, 1.0f);

    attn_v8<<<B_ * H_ * (L_ / 128), dim3(256), 0, stream>>>(
        Qw, Kw, Vtw, mask, relg, Ctxw, attn0);

    gemm_v2<2, __bf16><<<ngemm, dim3(512), 0, stream>>>(Ctxw, Wo, bo, out, M, D_, D_, 1.0f);
}

// Round 13
// 230.384 us; speedup vs baseline: 1.7651x; 1.1378x over previous
//
#include <hip/hip_runtime.h>
#include <hip/hip_bf16.h>

typedef __bf16 bf16x8 __attribute__((ext_vector_type(8)));
typedef __bf16 bf16x4 __attribute__((ext_vector_type(4)));
typedef float f32x4 __attribute__((ext_vector_type(4)));
typedef float f32x8 __attribute__((ext_vector_type(8)));

#define B_ 8
#define L_ 1024
#define D_ 1024
#define H_ 16
#define DPH_ 64
#define MAXREL_ 32
#define NREL_ 65

__device__ __forceinline__ f32x4 mfma16x16x32(bf16x8 a, bf16x8 b, f32x4 c) {
    return __builtin_amdgcn_mfma_f32_16x16x32_bf16(a, b, c, 0, 0, 0);
}

__device__ __forceinline__ bf16x8 ld_any(const float* p) {
    f32x8 v = *(const f32x8*)p;
    bf16x8 r;
    #pragma unroll
    for (int i = 0; i < 8; ++i) r[i] = (__bf16)v[i];
    return r;
}
__device__ __forceinline__ bf16x8 ld_any(const __bf16* p) { return *(const bf16x8*)p; }

// ---------------------------------------------------------------------------
// f32 -> bf16 weight converters.
// ---------------------------------------------------------------------------
__global__ __launch_bounds__(256) void cvt3(
    const float* __restrict__ a, const float* __restrict__ b,
    const float* __restrict__ c, __bf16* __restrict__ dst)
{
    const int gid = blockIdx.x * 256 + threadIdx.x;       // grid 1536 -> 393216
    const int arr = gid >> 17;                            // 131072 thr per 1M arr
    const int off = (gid & 131071) * 8;
    const float* src = arr == 0 ? a : (arr == 1 ? b : c);
    f32x8 v = *(const f32x8*)(src + off);
    bf16x8 r;
    #pragma unroll
    for (int i = 0; i < 8; ++i) r[i] = (__bf16)v[i];
    *(bf16x8*)(dst + ((size_t)arr << 20) + off) = r;
}

__global__ __launch_bounds__(256) void cvt1(
    const float* __restrict__ a, __bf16* __restrict__ dst)
{
    const int off = (blockIdx.x * 256 + threadIdx.x) * 8; // grid 512
    f32x8 v = *(const f32x8*)(a + off);
    bf16x8 r;
    #pragma unroll
    for (int i = 0; i < 8; ++i) r[i] = (__bf16)v[i];
    *(bf16x8*)(dst + off) = r;
}

// ---------------------------------------------------------------------------
// Shared GEMM body: 128x256 tile, BK=32, 512 thr / 8 waves (2Mx4N), dbuf LDS
// [rows][40] (2-way bank aliasing = free). mode 0: bf16 out[m*N+n];
// mode 1: bf16 Vt[(m>>10)<<20 | n*1024 | m&1023]; mode 2: f32 out[m*N+n].
// ---------------------------------------------------------------------------
template <typename TA, typename TB>
__device__ __forceinline__ void gemm_body(
    const TA* __restrict__ X, const TB* __restrict__ Wt,
    const float* __restrict__ bias, void* __restrict__ outp,
    const int row0, const int col0, const int mode, const float scale,
    __bf16* sA, __bf16* sB)
{
    const int K = 1024, N = 1024;
    const int tid = threadIdx.x;
    const int lane = tid & 63, w = tid >> 6, lr = lane & 15, lk = lane >> 4;
    const int wm = w >> 2, wn = w & 3;
    const int arow = tid >> 2, ak = (tid & 3) * 8;
    const int brow = tid >> 1, bk = (tid & 1) * 16;
    const TA* agp = X  + (size_t)(row0 + arow) * K + ak;
    const TB* bgp = Wt + (size_t)(col0 + brow) * K + bk;

    f32x4 acc[4][4];
    #pragma unroll
    for (int a = 0; a < 4; ++a)
        #pragma unroll
        for (int b = 0; b < 4; ++b) acc[a][b] = (f32x4){0.f, 0.f, 0.f, 0.f};

    f32x4 ra0, ra1; bf16x8 rab;
    f32x4 rb0, rb1, rb2, rb3; bf16x8 rbb0, rbb1;

    auto LOADG = [&](int t) {
        const int k0 = t * 32;
        if (sizeof(TA) == 4) {
            ra0 = *(const f32x4*)((const float*)agp + k0);
            ra1 = *(const f32x4*)((const float*)agp + k0 + 4);
        } else {
            rab = *(const bf16x8*)((const __bf16*)agp + k0);
        }
        if (sizeof(TB) == 4) {
            rb0 = *(const f32x4*)((const float*)bgp + k0);
            rb1 = *(const f32x4*)((const float*)bgp + k0 + 4);
            rb2 = *(const f32x4*)((const float*)bgp + k0 + 8);
            rb3 = *(const f32x4*)((const float*)bgp + k0 + 12);
        } else {
            rbb0 = *(const bf16x8*)((const __bf16*)bgp + k0);
            rbb1 = *(const bf16x8*)((const __bf16*)bgp + k0 + 8);
        }
    };
    auto WRITEL = [&](int buf) {
        bf16x8 av;
        if (sizeof(TA) == 4) {
            #pragma unroll
            for (int i = 0; i < 4; ++i) {
                av[i] = (__bf16)ra0[i]; av[4 + i] = (__bf16)ra1[i];
            }
        } else av = rab;
        *(bf16x8*)&sA[buf * (128 * 40) + arow * 40 + ak] = av;
        bf16x8 bv0, bv1;
        if (sizeof(TB) == 4) {
            #pragma unroll
            for (int i = 0; i < 4; ++i) {
                bv0[i] = (__bf16)rb0[i]; bv0[4 + i] = (__bf16)rb1[i];
                bv1[i] = (__bf16)rb2[i]; bv1[4 + i] = (__bf16)rb3[i];
            }
        } else { bv0 = rbb0; bv1 = rbb1; }
        *(bf16x8*)&sB[buf * (256 * 40) + brow * 40 + bk]     = bv0;
        *(bf16x8*)&sB[buf * (256 * 40) + brow * 40 + bk + 8] = bv1;
    };

    LOADG(0);
    WRITEL(0);
    LOADG(1);
    __syncthreads();

    const int nkt = K >> 5;   // 32
    for (int t = 0; t < nkt; ++t) {
        const int cur = t & 1;
        bf16x8 af[4], bfr[4];
        #pragma unroll
        for (int m = 0; m < 4; ++m)
            af[m] = *(const bf16x8*)&sA[cur * (128 * 40)
                     + (wm * 64 + m * 16 + lr) * 40 + 8 * lk];
        #pragma unroll
        for (int n = 0; n < 4; ++n)
            bfr[n] = *(const bf16x8*)&sB[cur * (256 * 40)
                     + (wn * 64 + n * 16 + lr) * 40 + 8 * lk];
        __builtin_amdgcn_s_setprio(1);
        #pragma unroll
        for (int m = 0; m < 4; ++m)
            #pragma unroll
            for (int n = 0; n < 4; ++n)
                acc[m][n] = mfma16x16x32(af[m], bfr[n], acc[m][n]);
        __builtin_amdgcn_s_setprio(0);
        if (t < nkt - 1) {
            WRITEL(cur ^ 1);
            if (t < nkt - 2) LOADG(t + 2);
            __syncthreads();
        }
    }

    #pragma unroll
    for (int ni = 0; ni < 4; ++ni) {
        const int n = col0 + wn * 64 + ni * 16 + lr;
        const float bv = bias[n];
        #pragma unroll
        for (int mi = 0; mi < 4; ++mi) {
            const int m0 = row0 + wm * 64 + mi * 16 + lk * 4;
            if (mode == 0) {
                #pragma unroll
                for (int i = 0; i < 4; ++i)
                    ((__bf16*)outp)[(size_t)(m0 + i) * N + n] =
                        (__bf16)((acc[mi][ni][i] + bv) * scale);
            } else if (mode == 1) {
                bf16x4 v4;
                #pragma unroll
                for (int i = 0; i < 4; ++i) v4[i] = (__bf16)(acc[mi][ni][i] + bv);
                *(bf16x4*)((__bf16*)outp + ((size_t)(m0 >> 10) << 20)
                           + (size_t)n * L_ + (m0 & 1023)) = v4;
            } else {
                #pragma unroll
                for (int i = 0; i < 4; ++i)
                    ((float*)outp)[(size_t)(m0 + i) * N + n] = acc[mi][ni][i] + bv;
            }
        }
    }
}

// Fused QKV: 768 blocks; per-XCD z-grouping so each XCD streams one W at a
// time (fix for R6's W-panel L2 thrash) while 2-resident blocks cover the
// barrier drains. Wb = 3 x [1024][1024] bf16 consecutive.
__global__ __launch_bounds__(512, 2) void gemm_qkv_fused(
    const float* __restrict__ Xq, const float* __restrict__ Xk,
    const float* __restrict__ Xv, const __bf16* __restrict__ Wb,
    const float* __restrict__ bq, const float* __restrict__ bk,
    const float* __restrict__ bv,
    __bf16* __restrict__ Qw, __bf16* __restrict__ Kw, __bf16* __restrict__ Vtw)
{
    __shared__ __bf16 sA[2 * 128 * 40];
    __shared__ __bf16 sB[2 * 256 * 40];
    const int bid = (int)blockIdx.x;
    const int xcd = bid & 7, idx = bid >> 3;
    const int z = idx >> 5, t = idx & 31;
    const int tile = xcd * 32 + t;                 // 0..255
    const int row0 = (tile >> 2) * 128, col0 = (tile & 3) * 256;
    const float* X = z == 0 ? Xq : (z == 1 ? Xk : Xv);
    const __bf16* Wt = Wb + ((size_t)z << 20);
    const float* bias = z == 0 ? bq : (z == 1 ? bk : bv);
    void* outp = z == 0 ? (void*)Qw : (z == 1 ? (void*)Kw : (void*)Vtw);
    gemm_body<float, __bf16>(X, Wt, bias, outp, row0, col0,
                             z == 2 ? 1 : 0, z == 0 ? 0.125f : 1.0f, sA, sB);
}

// Single GEMM (out-projection): A bf16, W bf16, f32 out.
__global__ __launch_bounds__(512, 2) void gemm_out_k(
    const __bf16* __restrict__ X, const __bf16* __restrict__ Wt,
    const float* __restrict__ bias, float* __restrict__ outp)
{
    __shared__ __bf16 sA[2 * 128 * 40];
    __shared__ __bf16 sB[2 * 256 * 40];
    const int wg = (int)blockIdx.x;                // 256 blocks
    const int row0 = (wg >> 2) * 128, col0 = (wg & 3) * 256;
    gemm_body<__bf16, __bf16>(X, Wt, bias, outp, row0, col0, 2, 1.0f, sA, sB);
}

// ---------------------------------------------------------------------------
// Attention v5 (R8/R10-measured best, verbatim): block = (b, h, 64 q-rows),
// 4 waves; wave w owns q-rows [w*16, w*16+16) across ALL 1024 keys.
// ---------------------------------------------------------------------------
__global__ __launch_bounds__(256, 3) void attn_v5(
    const __bf16* __restrict__ Q, const __bf16* __restrict__ K,
    const __bf16* __restrict__ Vt, const int* __restrict__ mask,
    const float* __restrict__ relg, __bf16* __restrict__ ctx,
    float* __restrict__ attn0)
{
    __shared__ __bf16 sK[2][64 * 64];     // [key][d], chunk-swizzled
    __shared__ __bf16 sV[2][64 * 64];     // [d][key], chunk-swizzled
    __shared__ __bf16 s_rq[64 * 72];      // rq[qlocal][j], bf16
    __shared__ __bf16 s_arel[64 * 72];    // arel[qlocal][bucket], bf16
    __shared__ float s_sums[64];
    __shared__ unsigned s_mbits[32];

    const int tid = threadIdx.x;
    const int wg = ((int)blockIdx.x & 7) * 256 + ((int)blockIdx.x >> 3);
    const int qt = wg & 15, h = (wg >> 4) & 15, b = wg >> 8;
    const int q0 = qt * 64;
    const int lane = tid & 63, w = tid >> 6, lr = lane & 15, lk = lane >> 4;
    const size_t bh = (size_t)b * (L_ * D_) + (size_t)h * DPH_;
    const int qw = q0 + w * 16;           // wave's q base (global)
    const int ql = w * 16;                // wave's q base (block-local)

    const int strow = tid >> 3;                  // 0..31
    const int scg   = (tid & 7) ^ (strow & 7);   // pre-swizzled global chunk
    const __bf16* Kgp = K + bh + (size_t)strow * D_ + scg * 8;
    const __bf16* Vgp = Vt + ((size_t)b << 20)
                      + (size_t)(h * DPH_ + strow) * L_ + scg * 8;

    const __bf16* qp = Q + bh + (size_t)(qw + lr) * D_ + 8 * lk;
    const bf16x8 qf0 = *(const bf16x8*)qp;
    const bf16x8 qf1 = *(const bf16x8*)(qp + 32);

    #pragma unroll
    for (int rr = 0; rr < 4; ++rr) {
        const int k = rr * 256 + w * 64 + lane;
        const unsigned long long bal = __ballot(mask[b * L_ + k] != 0);
        if (lane == 0) {
            s_mbits[rr * 8 + w * 2]     = (unsigned)bal;
            s_mbits[rr * 8 + w * 2 + 1] = (unsigned)(bal >> 32);
        }
    }
    for (int i = tid; i < 64 * 72; i += 256) s_arel[i] = (__bf16)0.f;

    #pragma unroll
    for (int jt = 0; jt < 5; ++jt) {
        const int jr = jt * 16 + lr;
        const int jc = jr > 64 ? 64 : jr;
        const float* rp = relg + jc * 64 + 8 * lk;
        f32x4 rq = {0.f, 0.f, 0.f, 0.f};
        rq = mfma16x16x32(ld_any(rp), qf0, rq);
        rq = mfma16x16x32(ld_any(rp + 32), qf1, rq);
        #pragma unroll
        for (int i = 0; i < 4; ++i) {
            const int jj = jt * 16 + lk * 4 + i;
            if (jj <= 64) s_rq[(ql + lr) * 72 + jj] = (__bf16)rq[i];
        }
    }

    bf16x8 rk0 = *(const bf16x8*)(Kgp);
    bf16x8 rk1 = *(const bf16x8*)(Kgp + 32 * (size_t)D_);
    bf16x8 rv0 = *(const bf16x8*)(Vgp);
    bf16x8 rv1 = *(const bf16x8*)(Vgp + 32 * (size_t)L_);
    __syncthreads();

    const float rq0  = (float)s_rq[(ql + lr) * 72 + 0];
    const float rq64 = (float)s_rq[(ql + lr) * 72 + 64];

    float sum = 0.f, c0 = 0.f, c64 = 0.f;
    f32x4 pvacc[4];
    #pragma unroll
    for (int dt = 0; dt < 4; ++dt) pvacc[dt] = (f32x4){0.f, 0.f, 0.f, 0.f};
    float* a0p = attn0 + ((size_t)b * L_ + qw + lr) * L_;
    const int sw = lr & 7;
    const int s0l = lr + 32 * (lk & 1);
    const int s1l = s0l + 16;
    const bool hisel = (lk >> 1) != 0;

    for (int it = 0; it < 16; ++it) {
        const int cur = it & 1;
        const int k0 = it * 64;
        {
            __bf16* kd = &sK[cur][tid * 8];
            __bf16* vd = &sV[cur][tid * 8];
            *(bf16x8*)kd = rk0;  *(bf16x8*)(kd + 2048) = rk1;
            *(bf16x8*)vd = rv0;  *(bf16x8*)(vd + 2048) = rv1;
        }
        __syncthreads();
        if (it < 15) {
            const size_t ko = (size_t)(k0 + 64) * D_;
            rk0 = *(const bf16x8*)(Kgp + ko);
            rk1 = *(const bf16x8*)(Kgp + ko + 32 * (size_t)D_);
            rv0 = *(const bf16x8*)(Vgp + k0 + 64);
            rv1 = *(const bf16x8*)(Vgp + k0 + 64 + 32 * (size_t)L_);
        }

        const __bf16* kb = sK[cur];
        const __bf16* vb = sV[cur];

        float p[4][4];
        #pragma unroll
        for (int kt = 0; kt < 4; ++kt) {
            const int rb = (kt * 16 + lr) * 64;
            const bf16x8 a0 = *(const bf16x8*)&kb[rb + ((lk ^ sw) * 8)];
            const bf16x8 a1 = *(const bf16x8*)&kb[rb + (((lk + 4) ^ sw) * 8)];
            f32x4 acc = {0.f, 0.f, 0.f, 0.f};
            acc = mfma16x16x32(a0, qf0, acc);
            acc = mfma16x16x32(a1, qf1, acc);
            #pragma unroll
            for (int i = 0; i < 4; ++i) p[kt][i] = acc[i];
        }

        const unsigned mw0 = s_mbits[(k0 >> 5)];
        const unsigned mw1 = s_mbits[(k0 >> 5) + 1];
        const int side = (k0 <= qw - 95) ? -1 : ((k0 >= qw + 47) ? 1 : 0);
        if (side == 0) {
            #pragma unroll
            for (int kt = 0; kt < 4; ++kt) {
                const unsigned mword = kt < 2 ? mw0 : mw1;
                #pragma unroll
                for (int i = 0; i < 4; ++i) {
                    const int k = k0 + kt * 16 + lk * 4 + i;
                    const int dd = k - (qw + lr);
                    int j = dd + MAXREL_;
                    j = j < 0 ? 0 : (j > 64 ? 64 : j);
                    const float bias = (float)s_rq[(ql + lr) * 72 + j];
                    const float e = ((mword >> (k & 31)) & 1u)
                                  ? 0.f : __expf(p[kt][i] + bias);
                    p[kt][i] = e;
                    sum += e;
                    if (dd <= -MAXREL_)      c0  += e;
                    else if (dd >= MAXREL_)  c64 += e;
                    else s_arel[(ql + lr) * 72 + dd + MAXREL_] = (__bf16)e;
                }
            }
        } else {
            const float bias = side < 0 ? rq0 : rq64;
            float cacc = 0.f;
            #pragma unroll
            for (int kt = 0; kt < 4; ++kt) {
                const unsigned mword = kt < 2 ? mw0 : mw1;
                #pragma unroll
                for (int i = 0; i < 4; ++i) {
                    const int k = k0 + kt * 16 + lk * 4 + i;
                    const float e = ((mword >> (k & 31)) & 1u)
                                  ? 0.f : __expf(p[kt][i] + bias);
                    p[kt][i] = e;
                    cacc += e;
                }
            }
            sum += cacc;
            if (side < 0) c0 += cacc; else c64 += cacc;
        }

        if (h == 0) {
            #pragma unroll
            for (int kt = 0; kt < 4; ++kt) {
                f32x4 st;
                #pragma unroll
                for (int i = 0; i < 4; ++i) st[i] = p[kt][i];
                *(f32x4*)&a0p[k0 + kt * 16 + lk * 4] = st;
            }
        }

        unsigned pk[4][2];
        #pragma unroll
        for (int kt = 0; kt < 4; ++kt)
            #pragma unroll
            for (int hf = 0; hf < 2; ++hf) {
                union { unsigned u; __bf16 x[2]; } t;
                t.x[0] = (__bf16)p[kt][2 * hf];
                t.x[1] = (__bf16)p[kt][2 * hf + 1];
                pk[kt][hf] = t.u;
            }

        #pragma unroll
        for (int s = 0; s < 2; ++s) {
            union { unsigned u[4]; bf16x8 v; } ua;
            {
                const unsigned aE0 = __shfl((int)pk[2 * s][0],     s0l, 64);
                const unsigned aO0 = __shfl((int)pk[2 * s + 1][0], s0l, 64);
                const unsigned aE1 = __shfl((int)pk[2 * s][1],     s0l, 64);
                const unsigned aO1 = __shfl((int)pk[2 * s + 1][1], s0l, 64);
                const unsigned bE0 = __shfl((int)pk[2 * s][0],     s1l, 64);
                const unsigned bO0 = __shfl((int)pk[2 * s + 1][0], s1l, 64);
                const unsigned bE1 = __shfl((int)pk[2 * s][1],     s1l, 64);
                const unsigned bO1 = __shfl((int)pk[2 * s + 1][1], s1l, 64);
                ua.u[0] = hisel ? aO0 : aE0;
                ua.u[1] = hisel ? aO1 : aE1;
                ua.u[2] = hisel ? bO0 : bE0;
                ua.u[3] = hisel ? bO1 : bE1;
            }
            #pragma unroll
            for (int dt = 0; dt < 4; ++dt) {
                const bf16x8 bfv = *(const bf16x8*)
                    &vb[(dt * 16 + lr) * 64 + (((4 * s + lk) ^ sw) * 8)];
                pvacc[dt] = mfma16x16x32(ua.v, bfv, pvacc[dt]);
            }
        }
    }

    sum += __shfl_xor(sum, 16, 64); sum += __shfl_xor(sum, 32, 64);
    c0  += __shfl_xor(c0, 16, 64);  c0  += __shfl_xor(c0, 32, 64);
    c64 += __shfl_xor(c64, 16, 64); c64 += __shfl_xor(c64, 32, 64);
    if (lane < 16) {
        s_sums[ql + lr] = sum;
        s_arel[(ql + lr) * 72 + 0]  = (__bf16)c0;
        s_arel[(ql + lr) * 72 + 64] = (__bf16)c64;
    }
    __syncthreads();

    __bf16* rT = (__bf16*)sK;      // [64][72]
    for (int i = tid; i < NREL_ * DPH_; i += 256)
        rT[(i & 63) * 72 + (i >> 6)] = (__bf16)relg[i];
    __syncthreads();

    const bf16x8 af1 = *(const bf16x8*)&s_arel[(ql + lr) * 72 + 8 * lk];
    const bf16x8 af2 = *(const bf16x8*)&s_arel[(ql + lr) * 72 + 32 + 8 * lk];
    float a64[4], inv[4];
    #pragma unroll
    for (int i = 0; i < 4; ++i) {
        a64[i] = (float)s_arel[(ql + lk * 4 + i) * 72 + 64];
        inv[i] = 1.f / s_sums[ql + lk * 4 + i];
    }
    #pragma unroll
    for (int dt = 0; dt < 4; ++dt) {
        const bf16x8 b1 = *(const bf16x8*)&rT[(dt * 16 + lr) * 72 + 8 * lk];
        const bf16x8 b2 = *(const bf16x8*)&rT[(dt * 16 + lr) * 72 + 32 + 8 * lk];
        pvacc[dt] = mfma16x16x32(af1, b1, pvacc[dt]);
        pvacc[dt] = mfma16x16x32(af2, b2, pvacc[dt]);
        const float r64 = (float)rT[(dt * 16 + lr) * 72 + 64];
        #pragma unroll
        for (int i = 0; i < 4; ++i) {
            const float outv = (pvacc[dt][i] + a64[i] * r64) * inv[i];
            ctx[((size_t)b * L_ + q0 + ql + lk * 4 + i) * D_
                + h * DPH_ + dt * 16 + lr] = (__bf16)outv;
        }
    }

    if (h == 0) {
        #pragma unroll 4
        for (int n = 0; n < 16; ++n) {
            const float invr = 1.f / s_sums[ql + n];
            float* ap = attn0 + ((size_t)b * L_ + q0 + ql + n) * L_ + lane * 16;
            #pragma unroll
            for (int c = 0; c < 4; ++c) {
                f32x4 v = *(f32x4*)&ap[c * 4];
                #pragma unroll
                for (int i = 0; i < 4; ++i) v[i] *= invr;
                *(f32x4*)&ap[c * 4] = v;
            }
        }
    }
}

extern "C" void kernel_launch(void* const* d_in, const int* in_sizes, int n_in,
                              void* d_out, int out_size, void* d_ws, size_t ws_size,
                              hipStream_t stream) {
    const float* key   = (const float*)d_in[0];
    const float* value = (const float*)d_in[1];
    const float* query = (const float*)d_in[2];
    const int*   mask  = (const int*)d_in[3];
    const float* Wq = (const float*)d_in[4];
    const float* bq = (const float*)d_in[5];
    const float* Wk = (const float*)d_in[6];
    const float* bk = (const float*)d_in[7];
    const float* Wv = (const float*)d_in[8];
    const float* bv = (const float*)d_in[9];
    const float* Wo = (const float*)d_in[10];
    const float* bo = (const float*)d_in[11];
    const float* relg = (const float*)d_in[12];

    float* out   = (float*)d_out;
    float* attn0 = out + (size_t)B_ * L_ * D_;

    char* ws = (char*)d_ws;
    __bf16* Qw   = (__bf16*)(ws);                      // 16MB; Wo-bf16 later
    __bf16* Kw   = (__bf16*)(ws + ((size_t)16 << 20));
    __bf16* Vtw  = (__bf16*)(ws + ((size_t)32 << 20));
    __bf16* Ctxw = (__bf16*)(ws + ((size_t)48 << 20)); // Wqkv-bf16 first, ctx later
    __bf16* Wb   = (__bf16*)(ws + ((size_t)48 << 20)); // 3 x 2MB
    __bf16* Wob  = (__bf16*)(ws);                      // 2MB, in dead Qw region

    // 1. Wq/Wk/Wv -> bf16 (stashed where ctx will later live)
    cvt3<<<1536, 256, 0, stream>>>(Wq, Wk, Wv, Wb);

    // 2. fused QKV projections (per-XCD z-grouping)
    gemm_qkv_fused<<<768, dim3(512), 0, stream>>>(
        query, key, value, Wb, bq, bk, bv, Qw, Kw, Vtw);

    // 3. attention (v5, measured 130us)
    attn_v5<<<B_ * H_ * (L_ / 64), dim3(256), 0, stream>>>(
        Qw, Kw, Vtw, mask, relg, Ctxw, attn0);

    // 4. Wo -> bf16 into the dead Qw region, then out-projection
    cvt1<<<512, 256, 0, stream>>>(Wo, Wob);
    gemm_out_k<<<256, dim3(512), 0, stream>>>(Ctxw, Wob, bo, out);
}